// Round 2
// baseline (2701.261 us; speedup 1.0000x reference)
//
#include <hip/hip_runtime.h>
#include <cstdint>
#include <cstddef>

// B=256, T=512, D=64, H=256, G=1024. Two-layer LSTM + FC.
// TCH=32 chunks; per iteration one fused gemm dispatch (both layers) and one
// fused rec dispatch (layer0 chunk i on blocks 0-15, layer1 chunk i-1 on 16-31).
// R5: W_hh fully CU-resident in the rec kernel: k-frags 0-1 in LDS (128 KB,
// per-wave frag-order), k-frags 2-7 in 192 persistent VGPRs.
// R6: per-step barrier gated on lgkmcnt only; coalesced h0c store from LDS.
// R7: (a) t-loop pinned to unroll 2 (32x unroll blew the 32 KiB L1 I$ -- the
// ~40% idle signature), (b) gate-outer/kf-inner MFMA with preloaded a-frags so
// each gate's exp/rcp overlaps the next gate's MFMA chains, (c) v_cvt_pk_bf16
// replaces manual RNE f2bf in the h write (-24 VALU/thread/step).
#define GATES 1024
#define SEQT  512
#define TCH   32
#define NCH   16
#define XPSTEP 262144   // elements per timestep in rec-order xp: 16*512*32

using u16 = unsigned short;
using bf16x8 = __attribute__((ext_vector_type(8))) short;   // 8 bf16 = 4 VGPRs
using f32x4  = __attribute__((ext_vector_type(4))) float;

__device__ __forceinline__ float bf2f(u16 u) {
    union { float f; unsigned int i; } v; v.i = ((unsigned int)u) << 16; return v.f;
}
__device__ __forceinline__ u16 f2bf(float f) {
    union { float f; unsigned int i; } v; v.f = f;
    unsigned int r = v.i + 0x7FFFu + ((v.i >> 16) & 1u);   // RNE
    return (u16)(r >> 16);
}
// overflow-safe fast activations (v_exp + v_rcp, ~1 ulp)
__device__ __forceinline__ float sigm(float x) {
    return __builtin_amdgcn_rcpf(1.f + __expf(-x));
}
__device__ __forceinline__ float tanh_f(float x) {
    return 1.f - 2.f * __builtin_amdgcn_rcpf(1.f + __expf(2.f * x));
}

// ---------------- prep ----------------
__global__ void k_conv(const float* __restrict__ src, u16* __restrict__ dst, int n) {
    int i = blockIdx.x * 256 + threadIdx.x;
    if (i < n) dst[i] = f2bf(src[i]);
}
__global__ void k_bias(const float* __restrict__ a, const float* __restrict__ b,
                       float* __restrict__ o, int n) {
    int i = blockIdx.x * 256 + threadIdx.x;
    if (i < n) o[i] = a[i] + b[i];
}

// ---------------- fused input-projection GEMM (unchanged from R4) ----------
__global__ __launch_bounds__(256, 2) void gemm_fused(
    const u16* __restrict__ A0, const u16* __restrict__ W0,
    const float* __restrict__ b0, u16* __restrict__ o0, int t00,
    const u16* __restrict__ A1, const u16* __restrict__ W1,
    const float* __restrict__ b1, u16* __restrict__ o1, int it)
{
    const int half = blockIdx.x >> 9;
    if (half == 0 && it >= NCH) return;
    if (half == 1 && it == 0) return;
    const int bid = blockIdx.x & 511;

    const u16* A; const u16* W; const float* bias; u16* out;
    int K, As_b, As_t, t0;
    if (half == 0) { A = A0; W = W0; bias = b0; out = o0; K = 64;  As_b = 32768; As_t = 64;    t0 = t00; }
    else           { A = A1; W = W1; bias = b1; out = o1; K = 256; As_b = 256;   As_t = 65536; t0 = 0;   }

    __shared__ __align__(16) u16 As[128][40];
    __shared__ __align__(16) u16 Bs[128][40];
    const int tid  = threadIdx.x;
    const int mb   = bid >> 3, nb = bid & 7;
    const int n0   = nb * 128;
    const int wave = tid >> 6, lane = tid & 63;
    const int wm   = wave >> 1, wn = wave & 1;
    const int ml   = lane & 15, q = lane >> 4;
    const int tloc = mb >> 1;
    const int tt   = t0 + tloc;
    const int bbas = (mb & 1) * 128;

    f32x4 acc[4][4];
    #pragma unroll
    for (int mi = 0; mi < 4; ++mi)
        #pragma unroll
        for (int ni = 0; ni < 4; ++ni)
            acc[mi][ni] = (f32x4)0.f;

    const int nk = K >> 5;
    for (int kt = 0; kt < nk; ++kt) {
        __syncthreads();
        #pragma unroll
        for (int i = 0; i < 2; ++i) {
            int c = tid + i * 256;
            int row = c >> 2, kb = c & 3;
            *(uint4*)&As[row][kb * 8] = *(const uint4*)(
                A + (size_t)(bbas + row) * As_b + (size_t)tt * As_t + kt * 32 + kb * 8);
            *(uint4*)&Bs[row][kb * 8] = *(const uint4*)(
                W + (size_t)(n0 + row) * K + kt * 32 + kb * 8);
        }
        __syncthreads();
        bf16x8 af[4], bfr[4];
        #pragma unroll
        for (int mi = 0; mi < 4; ++mi)
            af[mi] = *(const bf16x8*)&As[wm * 64 + mi * 16 + ml][q * 8];
        #pragma unroll
        for (int ni = 0; ni < 4; ++ni)
            bfr[ni] = *(const bf16x8*)&Bs[wn * 64 + ni * 16 + ml][q * 8];
        #pragma unroll
        for (int mi = 0; mi < 4; ++mi)
            #pragma unroll
            for (int ni = 0; ni < 4; ++ni)
                acc[mi][ni] = __builtin_amdgcn_mfma_f32_16x16x32_bf16(
                    af[mi], bfr[ni], acc[mi][ni], 0, 0, 0);
    }

    #pragma unroll
    for (int ni = 0; ni < 4; ++ni) {
        int gc = n0 + wn * 64 + ni * 16 + ml;
        int gi = gc >> 8, u = gc & 255;
        int w = u >> 5, s = (u >> 4) & 1, mlr = u & 15;
        float bv = bias[gc];
        #pragma unroll
        for (int mi = 0; mi < 4; ++mi) {
            int b0r = bbas + wm * 64 + mi * 16 + q * 4;
            #pragma unroll
            for (int rr = 0; rr < 4; ++rr) {
                int bb = b0r + rr;
                int blk = bb >> 4, qr = (bb >> 2) & 3, r_r = bb & 3;
                size_t el = ((size_t)((tloc * 16 + blk) * 512 + w * 64 + qr * 16 + mlr)) * 32
                            + gi * 8 + s * 4 + r_r;
                out[el] = f2bf(acc[mi][ni][rr] + bv);
            }
        }
    }
}

// ---------------- fused LSTM recurrence, W fully CU-resident ----------------
// Blocks 0-15: layer0 chunk it; blocks 16-31: layer1 chunk it-1.
// Wave owns 128 gate rows. W k-frags 0-1 staged once into LDS (per-wave
// frag-order, contiguous per lane); k-frags 2-7 live in wreg[6][8] (192 VGPR).
// hA double-buffered: step t reads buf t&1, writes buf (t+1)&1, ONE raw
// barrier gated only on lgkmcnt (hA ds_writes).
__global__ __launch_bounds__(512, 1) void lstm_rec2(
    const u16* __restrict__ xp0, const u16* __restrict__ xp1,
    const u16* __restrict__ W0,  const u16* __restrict__ W1,
    u16* __restrict__ h0c, float* __restrict__ hlast,
    u16* __restrict__ hs0, float* __restrict__ cs0,
    u16* __restrict__ hs1, float* __restrict__ cs1, int it)
{
    const int L   = blockIdx.x >> 4;
    const int blk = blockIdx.x & 15;
    if (L == 0 && it >= NCH) return;
    if (L == 1 && it == 0) return;
    const int chunk = L ? it - 1 : it;
    const u16* xp = L ? xp1 : xp0;
    const u16* W  = L ? W1 : W0;
    u16*  hs = L ? hs1 : hs0;
    float* cs = L ? cs1 : cs0;
    const int init = (chunk == 0);

    __shared__ __align__(16) u16 WL[8 * 16 * 64 * 8];   // 131072 B, per-wave frag-order
    __shared__ __align__(16) u16 hA[2][16][264];        // 16896 B, double buffer

    const int tid  = threadIdx.x;
    const int wave = tid >> 6, lane = tid & 63;
    const int ml   = lane & 15, q = lane >> 4;
    const int ub   = wave * 32;
    const int bb0  = blk * 16;

    // W fragment element offsets: frag f = gi*2+s -> gate rows g
    int woff_[8];
    #pragma unroll
    for (int gi = 0; gi < 4; ++gi)
        #pragma unroll
        for (int s = 0; s < 2; ++s)
            woff_[gi * 2 + s] = (gi * 256 + ub + s * 16 + ml) * 256 + q * 8;

    // stage W k-frags 0-1 into LDS (each lane round-trips its own 16 B)
    const int wlb = (wave * 1024 + lane) * 8;   // element index of this lane's slot 0
    #pragma unroll
    for (int kf = 0; kf < 2; ++kf)
        #pragma unroll
        for (int f = 0; f < 8; ++f)
            *(bf16x8*)&WL[wlb + (kf * 8 + f) * 512] =
                *(const bf16x8*)(W + woff_[f] + kf * 32);

    // W k-frags 2-7 persistent in registers (192 VGPR)
    bf16x8 wreg[6][8];
    #pragma unroll
    for (int kf = 2; kf < 8; ++kf)
        #pragma unroll
        for (int f = 0; f < 8; ++f)
            wreg[kf - 2][f] = *(const bf16x8*)(W + woff_[f] + kf * 32);

    float c_[8];
    if (init) {
        for (int i = tid; i < 16 * 264; i += 512) ((u16*)&hA[0][0][0])[i] = 0;
        #pragma unroll
        for (int i = 0; i < 8; ++i) c_[i] = 0.f;
    } else {
        int m = tid >> 5, j0 = (tid & 31) * 8;
        *(bf16x8*)&hA[0][m][j0] = *(const bf16x8*)&hs[(size_t)(bb0 + m) * 256 + j0];
        #pragma unroll
        for (int s = 0; s < 2; ++s)
            #pragma unroll
            for (int r = 0; r < 4; ++r)
                c_[s * 4 + r] = cs[(size_t)(bb0 + q * 4 + r) * 256 + ub + s * 16 + ml];
    }

    const u16* xpt = xp + ((size_t)blk * 512 + tid) * 32;   // + t*XPSTEP per step
    const int m_st = tid >> 5;           // coalesced h0c store: row
    const int j_st = (tid & 31) * 8;     // coalesced h0c store: col

    __syncthreads();

    #pragma unroll 2
    for (int t = 0; t < TCH; ++t) {
        const int br = t & 1, bw = br ^ 1;

        // xp for this step: issued now, consumed only in the activations
        bf16x8 xv[4];
        #pragma unroll
        for (int gi = 0; gi < 4; ++gi)
            xv[gi] = *(const bf16x8*)(xpt + gi * 8);

        // all 8 a-frags for this step, issued together
        bf16x8 a[8];
        #pragma unroll
        for (int kf = 0; kf < 8; ++kf)
            a[kf] = *(const bf16x8*)&hA[br][ml][kf * 32 + q * 8];

        // gate-outer / kf-inner: each gate's 2 chains (s=0,1) complete early,
        // its exp/rcp activation then overlaps the next gate's MFMA chains.
        float gv[4][2][4];
        #pragma unroll
        for (int gi = 0; gi < 4; ++gi) {
            f32x4 acc[2];
            acc[0] = (f32x4)0.f; acc[1] = (f32x4)0.f;
            #pragma unroll
            for (int s = 0; s < 2; ++s) {
                const int f = gi * 2 + s;
                #pragma unroll
                for (int kf = 0; kf < 2; ++kf) {
                    bf16x8 b = *(const bf16x8*)&WL[wlb + (kf * 8 + f) * 512];
                    acc[s] = __builtin_amdgcn_mfma_f32_16x16x32_bf16(
                        a[kf], b, acc[s], 0, 0, 0);
                }
                #pragma unroll
                for (int kf = 2; kf < 8; ++kf)
                    acc[s] = __builtin_amdgcn_mfma_f32_16x16x32_bf16(
                        a[kf], wreg[kf - 2][f], acc[s], 0, 0, 0);
            }
            #pragma unroll
            for (int s = 0; s < 2; ++s)
                #pragma unroll
                for (int r = 0; r < 4; ++r) {
                    float pre = acc[s][r] + bf2f((u16)xv[gi][s * 4 + r]);
                    gv[gi][s][r] = (gi == 2) ? tanh_f(pre) : sigm(pre);
                }
        }

        // cell update + bf16 pack (v_cvt_pk_bf16_f32, RNE)
        #pragma unroll
        for (int s = 0; s < 2; ++s) {
            const int j = ub + s * 16 + ml;
            float hv[4];
            #pragma unroll
            for (int r = 0; r < 4; ++r) {
                float cc = gv[1][s][r] * c_[s * 4 + r] + gv[0][s][r] * gv[2][s][r];
                c_[s * 4 + r] = cc;
                hv[r] = gv[3][s][r] * tanh_f(cc);
            }
            unsigned p01, p23;
            asm("v_cvt_pk_bf16_f32 %0, %1, %2" : "=v"(p01) : "v"(hv[0]), "v"(hv[1]));
            asm("v_cvt_pk_bf16_f32 %0, %1, %2" : "=v"(p23) : "v"(hv[2]), "v"(hv[3]));
            hA[bw][q * 4 + 0][j] = (u16)p01;
            hA[bw][q * 4 + 1][j] = (u16)(p01 >> 16);
            hA[bw][q * 4 + 2][j] = (u16)p23;
            hA[bw][q * 4 + 3][j] = (u16)(p23 >> 16);
            if (L == 1 && chunk == NCH - 1 && t == TCH - 1) {
                #pragma unroll
                for (int r = 0; r < 4; ++r)
                    hlast[(size_t)(bb0 + q * 4 + r) * 256 + j] = hv[r];
            }
        }
        xpt += XPSTEP;

        // publish h(t+1): only the hA ds_writes gate the barrier. Global xp
        // loads and h0c stores stay in flight across it (no vmcnt drain).
        asm volatile("s_waitcnt lgkmcnt(0)\n\ts_barrier" ::: "memory");

        // h for step t is now complete in hA[bw]: one coalesced 16 B store
        // per thread (drains lazily; consumed only by next gemm dispatch).
        if (L == 0)
            *(bf16x8*)&h0c[((size_t)t * 256 + bb0 + m_st) * 256 + j_st] =
                *(const bf16x8*)&hA[bw][m_st][j_st];
    }

    // persist state (TCH even -> final h is in buf 0)
    #pragma unroll
    for (int s = 0; s < 2; ++s)
        #pragma unroll
        for (int r = 0; r < 4; ++r)
            cs[(size_t)(bb0 + q * 4 + r) * 256 + ub + s * 16 + ml] = c_[s * 4 + r];
    {
        int m = tid >> 5, j0 = (tid & 31) * 8;
        *(bf16x8*)&hs[(size_t)(bb0 + m) * 256 + j0] = *(const bf16x8*)&hA[0][m][j0];
    }
}

// ---------------- FC head ----------------
__global__ void fc_k(const float* __restrict__ h, const float* __restrict__ w,
                     const float* __restrict__ b, float* __restrict__ out)
{
    int bb = blockIdx.x, lane = threadIdx.x;
    float s = 0.f;
    for (int j = lane; j < 256; j += 64) s += h[bb * 256 + j] * w[j];
    #pragma unroll
    for (int off = 32; off > 0; off >>= 1) s += __shfl_down(s, off);
    if (lane == 0) out[bb] = s + b[0];
}

extern "C" void kernel_launch(void* const* d_in, const int* in_sizes, int n_in,
                              void* d_out, int out_size, void* d_ws, size_t ws_size,
                              hipStream_t stream)
{
    const float* x    = (const float*)d_in[0];
    const float* Wih0 = (const float*)d_in[1];
    const float* Whh0 = (const float*)d_in[2];
    const float* bih0 = (const float*)d_in[3];
    const float* bhh0 = (const float*)d_in[4];
    const float* Wih1 = (const float*)d_in[5];
    const float* Whh1 = (const float*)d_in[6];
    const float* bih1 = (const float*)d_in[7];
    const float* bhh1 = (const float*)d_in[8];
    const float* fcw  = (const float*)d_in[9];
    const float* fcb  = (const float*)d_in[10];
    float* out = (float*)d_out;

    // workspace layout, total ~57.3 MB
    char* ws = (char*)d_ws;
    u16*   xp0   = (u16*)(ws);                  // 16777216
    u16*   xp1   = (u16*)(ws + 16777216);       // 16777216
    u16*   h0c   = (u16*)(ws + 33554432);       //  4194304  [32][256][256] bf16
    u16*   xb    = (u16*)(ws + 37748736);       // 16777216  [256][512][64] bf16
    u16*   Wih0b = (u16*)(ws + 54525952);       //   131072
    u16*   Whh0b = (u16*)(ws + 54657024);       //   524288
    u16*   Wih1b = (u16*)(ws + 55181312);       //   524288
    u16*   Whh1b = (u16*)(ws + 55705600);       //   524288
    float* bias0 = (float*)(ws + 56229888);     //     4096
    float* bias1 = (float*)(ws + 56233984);     //     4096
    u16*   hs0   = (u16*)(ws + 56238080);       //   131072
    float* cs0   = (float*)(ws + 56369152);     //   262144
    u16*   hs1   = (u16*)(ws + 56631296);       //   131072
    float* cs1   = (float*)(ws + 56762368);     //   262144
    float* h1l   = (float*)(ws + 57024512);     //   262144

    k_conv<<<32768, 256, 0, stream>>>(x, xb, 8388608);
    k_conv<<<256,   256, 0, stream>>>(Wih0, Wih0b, 65536);
    k_conv<<<1024,  256, 0, stream>>>(Whh0, Whh0b, 262144);
    k_conv<<<1024,  256, 0, stream>>>(Wih1, Wih1b, 262144);
    k_conv<<<1024,  256, 0, stream>>>(Whh1, Whh1b, 262144);
    k_bias<<<4, 256, 0, stream>>>(bih0, bhh0, bias0, 1024);
    k_bias<<<4, 256, 0, stream>>>(bih1, bhh1, bias1, 1024);

    for (int it = 0; it <= NCH; ++it) {
        gemm_fused<<<1024, 256, 0, stream>>>(xb, Wih0b, bias0, xp0, it * TCH,
                                             h0c, Wih1b, bias1, xp1, it);
        lstm_rec2<<<32, 512, 0, stream>>>(xp0, xp1, Whh0b, Whh1b, h0c, h1l,
                                          hs0, cs0, hs1, cs1, it);
    }
    fc_k<<<256, 64, 0, stream>>>(h1l, fcw, fcb, out);
}

// Round 3
// 2603.844 us; speedup vs baseline: 1.0374x; 1.0374x over previous
//
#include <hip/hip_runtime.h>
#include <cstdint>
#include <cstddef>

// B=256, T=512, D=64, H=256, G=1024. Two-layer LSTM + FC.
// TCH=32 chunks; per iteration one fused gemm dispatch (both layers) and one
// fused rec dispatch (layer0 chunk i on blocks 0-15, layer1 chunk i-1 on 16-31).
// R6: per-step barrier gated on lgkmcnt only; coalesced h0c store from LDS.
// R8: VGPR_Count=128 exposed that the compiler had demoted wreg[6][8] (192
// VGPR can't fit its 128-reg heuristic) -> all 6 k-frags were re-LOADED from
// global W every step (48 loads/thread/step, L2 latency chained with MFMAs).
// Fix: amdgpu_waves_per_eu(2,2) pins the 256-VGPR budget; wreg holds k-frags
// 2-5 only (128 VGPR, genuinely fits); k-frags 6-7 are explicitly streamed as
// 16 dwordx4 issued at step top (latency hidden under kf0-5 MFMAs); k-frags
// 0-1 stay in LDS. Streamed L2 traffic per step drops 3x and is issue-batched.
#define GATES 1024
#define SEQT  512
#define TCH   32
#define NCH   16
#define XPSTEP 262144   // elements per timestep in rec-order xp: 16*512*32

using u16 = unsigned short;
using bf16x8 = __attribute__((ext_vector_type(8))) short;   // 8 bf16 = 4 VGPRs
using f32x4  = __attribute__((ext_vector_type(4))) float;

__device__ __forceinline__ float bf2f(u16 u) {
    union { float f; unsigned int i; } v; v.i = ((unsigned int)u) << 16; return v.f;
}
__device__ __forceinline__ u16 f2bf(float f) {
    union { float f; unsigned int i; } v; v.f = f;
    unsigned int r = v.i + 0x7FFFu + ((v.i >> 16) & 1u);   // RNE
    return (u16)(r >> 16);
}
// overflow-safe fast activations (v_exp + v_rcp, ~1 ulp)
__device__ __forceinline__ float sigm(float x) {
    return __builtin_amdgcn_rcpf(1.f + __expf(-x));
}
__device__ __forceinline__ float tanh_f(float x) {
    return 1.f - 2.f * __builtin_amdgcn_rcpf(1.f + __expf(2.f * x));
}

// ---------------- prep ----------------
__global__ void k_conv(const float* __restrict__ src, u16* __restrict__ dst, int n) {
    int i = blockIdx.x * 256 + threadIdx.x;
    if (i < n) dst[i] = f2bf(src[i]);
}
__global__ void k_bias(const float* __restrict__ a, const float* __restrict__ b,
                       float* __restrict__ o, int n) {
    int i = blockIdx.x * 256 + threadIdx.x;
    if (i < n) o[i] = a[i] + b[i];
}

// ---------------- fused input-projection GEMM (unchanged from R4) ----------
__global__ __launch_bounds__(256, 2) void gemm_fused(
    const u16* __restrict__ A0, const u16* __restrict__ W0,
    const float* __restrict__ b0, u16* __restrict__ o0, int t00,
    const u16* __restrict__ A1, const u16* __restrict__ W1,
    const float* __restrict__ b1, u16* __restrict__ o1, int it)
{
    const int half = blockIdx.x >> 9;
    if (half == 0 && it >= NCH) return;
    if (half == 1 && it == 0) return;
    const int bid = blockIdx.x & 511;

    const u16* A; const u16* W; const float* bias; u16* out;
    int K, As_b, As_t, t0;
    if (half == 0) { A = A0; W = W0; bias = b0; out = o0; K = 64;  As_b = 32768; As_t = 64;    t0 = t00; }
    else           { A = A1; W = W1; bias = b1; out = o1; K = 256; As_b = 256;   As_t = 65536; t0 = 0;   }

    __shared__ __align__(16) u16 As[128][40];
    __shared__ __align__(16) u16 Bs[128][40];
    const int tid  = threadIdx.x;
    const int mb   = bid >> 3, nb = bid & 7;
    const int n0   = nb * 128;
    const int wave = tid >> 6, lane = tid & 63;
    const int wm   = wave >> 1, wn = wave & 1;
    const int ml   = lane & 15, q = lane >> 4;
    const int tloc = mb >> 1;
    const int tt   = t0 + tloc;
    const int bbas = (mb & 1) * 128;

    f32x4 acc[4][4];
    #pragma unroll
    for (int mi = 0; mi < 4; ++mi)
        #pragma unroll
        for (int ni = 0; ni < 4; ++ni)
            acc[mi][ni] = (f32x4)0.f;

    const int nk = K >> 5;
    for (int kt = 0; kt < nk; ++kt) {
        __syncthreads();
        #pragma unroll
        for (int i = 0; i < 2; ++i) {
            int c = tid + i * 256;
            int row = c >> 2, kb = c & 3;
            *(uint4*)&As[row][kb * 8] = *(const uint4*)(
                A + (size_t)(bbas + row) * As_b + (size_t)tt * As_t + kt * 32 + kb * 8);
            *(uint4*)&Bs[row][kb * 8] = *(const uint4*)(
                W + (size_t)(n0 + row) * K + kt * 32 + kb * 8);
        }
        __syncthreads();
        bf16x8 af[4], bfr[4];
        #pragma unroll
        for (int mi = 0; mi < 4; ++mi)
            af[mi] = *(const bf16x8*)&As[wm * 64 + mi * 16 + ml][q * 8];
        #pragma unroll
        for (int ni = 0; ni < 4; ++ni)
            bfr[ni] = *(const bf16x8*)&Bs[wn * 64 + ni * 16 + ml][q * 8];
        #pragma unroll
        for (int mi = 0; mi < 4; ++mi)
            #pragma unroll
            for (int ni = 0; ni < 4; ++ni)
                acc[mi][ni] = __builtin_amdgcn_mfma_f32_16x16x32_bf16(
                    af[mi], bfr[ni], acc[mi][ni], 0, 0, 0);
    }

    #pragma unroll
    for (int ni = 0; ni < 4; ++ni) {
        int gc = n0 + wn * 64 + ni * 16 + ml;
        int gi = gc >> 8, u = gc & 255;
        int w = u >> 5, s = (u >> 4) & 1, mlr = u & 15;
        float bv = bias[gc];
        #pragma unroll
        for (int mi = 0; mi < 4; ++mi) {
            int b0r = bbas + wm * 64 + mi * 16 + q * 4;
            #pragma unroll
            for (int rr = 0; rr < 4; ++rr) {
                int bb = b0r + rr;
                int blk = bb >> 4, qr = (bb >> 2) & 3, r_r = bb & 3;
                size_t el = ((size_t)((tloc * 16 + blk) * 512 + w * 64 + qr * 16 + mlr)) * 32
                            + gi * 8 + s * 4 + r_r;
                out[el] = f2bf(acc[mi][ni][rr] + bv);
            }
        }
    }
}

// ---------------- fused LSTM recurrence, W genuinely CU-resident -----------
// Blocks 0-15: layer0 chunk it; blocks 16-31: layer1 chunk it-1.
// Wave owns 128 gate rows. W k-frags 0-1 in LDS (128 KB), k-frags 2-5 in 128
// persistent VGPRs (fits the 256-VGPR @ 2-waves/EU budget), k-frags 6-7
// streamed from L2 each step (16 dwordx4 issued at step top, consumed last).
__global__ __attribute__((amdgpu_flat_work_group_size(512, 512),
                          amdgpu_waves_per_eu(2, 2))) void lstm_rec2(
    const u16* __restrict__ xp0, const u16* __restrict__ xp1,
    const u16* __restrict__ W0,  const u16* __restrict__ W1,
    u16* __restrict__ h0c, float* __restrict__ hlast,
    u16* __restrict__ hs0, float* __restrict__ cs0,
    u16* __restrict__ hs1, float* __restrict__ cs1, int it)
{
    const int L   = blockIdx.x >> 4;
    const int blk = blockIdx.x & 15;
    if (L == 0 && it >= NCH) return;
    if (L == 1 && it == 0) return;
    const int chunk = L ? it - 1 : it;
    const u16* xp = L ? xp1 : xp0;
    const u16* W  = L ? W1 : W0;
    u16*  hs = L ? hs1 : hs0;
    float* cs = L ? cs1 : cs0;
    const int init = (chunk == 0);

    __shared__ __align__(16) u16 WL[8 * 16 * 64 * 8];   // 131072 B, per-wave frag-order
    __shared__ __align__(16) u16 hA[2][16][264];        // 16896 B, double buffer

    const int tid  = threadIdx.x;
    const int wave = tid >> 6, lane = tid & 63;
    const int ml   = lane & 15, q = lane >> 4;
    const int ub   = wave * 32;
    const int bb0  = blk * 16;

    // W fragment element offsets: frag f = gi*2+s -> gate rows g
    int woff_[8];
    #pragma unroll
    for (int gi = 0; gi < 4; ++gi)
        #pragma unroll
        for (int s = 0; s < 2; ++s)
            woff_[gi * 2 + s] = (gi * 256 + ub + s * 16 + ml) * 256 + q * 8;

    // stage W k-frags 0-1 into LDS (each lane round-trips its own 16 B)
    const int wlb = (wave * 1024 + lane) * 8;   // element index of this lane's slot 0
    #pragma unroll
    for (int kf = 0; kf < 2; ++kf)
        #pragma unroll
        for (int f = 0; f < 8; ++f)
            *(bf16x8*)&WL[wlb + (kf * 8 + f) * 512] =
                *(const bf16x8*)(W + woff_[f] + kf * 32);

    // W k-frags 2-5 persistent in registers (128 VGPR -- fits 256 budget)
    bf16x8 wreg[4][8];
    #pragma unroll
    for (int kf = 2; kf < 6; ++kf)
        #pragma unroll
        for (int f = 0; f < 8; ++f)
            wreg[kf - 2][f] = *(const bf16x8*)(W + woff_[f] + kf * 32);

    float c_[8];
    if (init) {
        for (int i = tid; i < 16 * 264; i += 512) ((u16*)&hA[0][0][0])[i] = 0;
        #pragma unroll
        for (int i = 0; i < 8; ++i) c_[i] = 0.f;
    } else {
        int m = tid >> 5, j0 = (tid & 31) * 8;
        *(bf16x8*)&hA[0][m][j0] = *(const bf16x8*)&hs[(size_t)(bb0 + m) * 256 + j0];
        #pragma unroll
        for (int s = 0; s < 2; ++s)
            #pragma unroll
            for (int r = 0; r < 4; ++r)
                c_[s * 4 + r] = cs[(size_t)(bb0 + q * 4 + r) * 256 + ub + s * 16 + ml];
    }

    const u16* xpt = xp + ((size_t)blk * 512 + tid) * 32;   // + t*XPSTEP per step
    const int m_st = tid >> 5;           // coalesced h0c store: row
    const int j_st = (tid & 31) * 8;     // coalesced h0c store: col

    __syncthreads();

    for (int t = 0; t < TCH; ++t) {
        const int br = t & 1, bw = br ^ 1;

        // long-latency loads first: xp (HBM) then streamed W k-frags 6-7 (L2).
        // All consumed late in the step -> latency hides under kf0-5 MFMAs.
        bf16x8 xv[4];
        #pragma unroll
        for (int gi = 0; gi < 4; ++gi)
            xv[gi] = *(const bf16x8*)(xpt + gi * 8);

        bf16x8 ws[2][8];
        #pragma unroll
        for (int kf = 0; kf < 2; ++kf)
            #pragma unroll
            for (int f = 0; f < 8; ++f)
                ws[kf][f] = *(const bf16x8*)(W + woff_[f] + (6 + kf) * 32);

        f32x4 acc[4][2];
        #pragma unroll
        for (int gi = 0; gi < 4; ++gi)
            #pragma unroll
            for (int s = 0; s < 2; ++s)
                acc[gi][s] = (f32x4)0.f;

        // k-frags 0-1 from LDS
        #pragma unroll
        for (int kf = 0; kf < 2; ++kf) {
            bf16x8 a = *(const bf16x8*)&hA[br][ml][kf * 32 + q * 8];
            #pragma unroll
            for (int f = 0; f < 8; ++f) {
                bf16x8 b = *(const bf16x8*)&WL[wlb + (kf * 8 + f) * 512];
                acc[f >> 1][f & 1] = __builtin_amdgcn_mfma_f32_16x16x32_bf16(
                    a, b, acc[f >> 1][f & 1], 0, 0, 0);
            }
        }
        // k-frags 2-5 from persistent registers
        #pragma unroll
        for (int kf = 2; kf < 6; ++kf) {
            bf16x8 a = *(const bf16x8*)&hA[br][ml][kf * 32 + q * 8];
            #pragma unroll
            for (int f = 0; f < 8; ++f)
                acc[f >> 1][f & 1] = __builtin_amdgcn_mfma_f32_16x16x32_bf16(
                    a, wreg[kf - 2][f], acc[f >> 1][f & 1], 0, 0, 0);
        }
        // k-frags 6-7 from the streamed registers (loads issued at step top)
        #pragma unroll
        for (int kf = 6; kf < 8; ++kf) {
            bf16x8 a = *(const bf16x8*)&hA[br][ml][kf * 32 + q * 8];
            #pragma unroll
            for (int f = 0; f < 8; ++f)
                acc[f >> 1][f & 1] = __builtin_amdgcn_mfma_f32_16x16x32_bf16(
                    a, ws[kf - 6][f], acc[f >> 1][f & 1], 0, 0, 0);
        }

        // activations
        float gv[4][2][4];
        #pragma unroll
        for (int gi = 0; gi < 4; ++gi)
            #pragma unroll
            for (int s = 0; s < 2; ++s)
                #pragma unroll
                for (int r = 0; r < 4; ++r) {
                    float pre = acc[gi][s][r] + bf2f((u16)xv[gi][s * 4 + r]);
                    gv[gi][s][r] = (gi == 2) ? tanh_f(pre) : sigm(pre);
                }

        // cell update + bf16 pack (v_cvt_pk_bf16_f32, RNE)
        #pragma unroll
        for (int s = 0; s < 2; ++s) {
            const int j = ub + s * 16 + ml;
            float hv[4];
            #pragma unroll
            for (int r = 0; r < 4; ++r) {
                float cc = gv[1][s][r] * c_[s * 4 + r] + gv[0][s][r] * gv[2][s][r];
                c_[s * 4 + r] = cc;
                hv[r] = gv[3][s][r] * tanh_f(cc);
            }
            unsigned p01, p23;
            asm("v_cvt_pk_bf16_f32 %0, %1, %2" : "=v"(p01) : "v"(hv[0]), "v"(hv[1]));
            asm("v_cvt_pk_bf16_f32 %0, %1, %2" : "=v"(p23) : "v"(hv[2]), "v"(hv[3]));
            hA[bw][q * 4 + 0][j] = (u16)p01;
            hA[bw][q * 4 + 1][j] = (u16)(p01 >> 16);
            hA[bw][q * 4 + 2][j] = (u16)p23;
            hA[bw][q * 4 + 3][j] = (u16)(p23 >> 16);
            if (L == 1 && chunk == NCH - 1 && t == TCH - 1) {
                #pragma unroll
                for (int r = 0; r < 4; ++r)
                    hlast[(size_t)(bb0 + q * 4 + r) * 256 + j] = hv[r];
            }
        }
        xpt += XPSTEP;

        // publish h(t+1): only the hA ds_writes gate the barrier. Global xp
        // loads and h0c stores stay in flight across it (no vmcnt drain).
        asm volatile("s_waitcnt lgkmcnt(0)\n\ts_barrier" ::: "memory");

        // h for step t is now complete in hA[bw]: one coalesced 16 B store
        // per thread (drains lazily; consumed only by next gemm dispatch).
        if (L == 0)
            *(bf16x8*)&h0c[((size_t)t * 256 + bb0 + m_st) * 256 + j_st] =
                *(const bf16x8*)&hA[bw][m_st][j_st];
    }

    // persist state (TCH even -> final h is in buf 0)
    #pragma unroll
    for (int s = 0; s < 2; ++s)
        #pragma unroll
        for (int r = 0; r < 4; ++r)
            cs[(size_t)(bb0 + q * 4 + r) * 256 + ub + s * 16 + ml] = c_[s * 4 + r];
    {
        int m = tid >> 5, j0 = (tid & 31) * 8;
        *(bf16x8*)&hs[(size_t)(bb0 + m) * 256 + j0] = *(const bf16x8*)&hA[0][m][j0];
    }
}

// ---------------- FC head ----------------
__global__ void fc_k(const float* __restrict__ h, const float* __restrict__ w,
                     const float* __restrict__ b, float* __restrict__ out)
{
    int bb = blockIdx.x, lane = threadIdx.x;
    float s = 0.f;
    for (int j = lane; j < 256; j += 64) s += h[bb * 256 + j] * w[j];
    #pragma unroll
    for (int off = 32; off > 0; off >>= 1) s += __shfl_down(s, off);
    if (lane == 0) out[bb] = s + b[0];
}

extern "C" void kernel_launch(void* const* d_in, const int* in_sizes, int n_in,
                              void* d_out, int out_size, void* d_ws, size_t ws_size,
                              hipStream_t stream)
{
    const float* x    = (const float*)d_in[0];
    const float* Wih0 = (const float*)d_in[1];
    const float* Whh0 = (const float*)d_in[2];
    const float* bih0 = (const float*)d_in[3];
    const float* bhh0 = (const float*)d_in[4];
    const float* Wih1 = (const float*)d_in[5];
    const float* Whh1 = (const float*)d_in[6];
    const float* bih1 = (const float*)d_in[7];
    const float* bhh1 = (const float*)d_in[8];
    const float* fcw  = (const float*)d_in[9];
    const float* fcb  = (const float*)d_in[10];
    float* out = (float*)d_out;

    // workspace layout, total ~57.3 MB
    char* ws = (char*)d_ws;
    u16*   xp0   = (u16*)(ws);                  // 16777216
    u16*   xp1   = (u16*)(ws + 16777216);       // 16777216
    u16*   h0c   = (u16*)(ws + 33554432);       //  4194304  [32][256][256] bf16
    u16*   xb    = (u16*)(ws + 37748736);       // 16777216  [256][512][64] bf16
    u16*   Wih0b = (u16*)(ws + 54525952);       //   131072
    u16*   Whh0b = (u16*)(ws + 54657024);       //   524288
    u16*   Wih1b = (u16*)(ws + 55181312);       //   524288
    u16*   Whh1b = (u16*)(ws + 55705600);       //   524288
    float* bias0 = (float*)(ws + 56229888);     //     4096
    float* bias1 = (float*)(ws + 56233984);     //     4096
    u16*   hs0   = (u16*)(ws + 56238080);       //   131072
    float* cs0   = (float*)(ws + 56369152);     //   262144
    u16*   hs1   = (u16*)(ws + 56631296);       //   131072
    float* cs1   = (float*)(ws + 56762368);     //   262144
    float* h1l   = (float*)(ws + 57024512);     //   262144

    k_conv<<<32768, 256, 0, stream>>>(x, xb, 8388608);
    k_conv<<<256,   256, 0, stream>>>(Wih0, Wih0b, 65536);
    k_conv<<<1024,  256, 0, stream>>>(Whh0, Whh0b, 262144);
    k_conv<<<1024,  256, 0, stream>>>(Wih1, Wih1b, 262144);
    k_conv<<<1024,  256, 0, stream>>>(Whh1, Whh1b, 262144);
    k_bias<<<4, 256, 0, stream>>>(bih0, bhh0, bias0, 1024);
    k_bias<<<4, 256, 0, stream>>>(bih1, bhh1, bias1, 1024);

    for (int it = 0; it <= NCH; ++it) {
        gemm_fused<<<1024, 256, 0, stream>>>(xb, Wih0b, bias0, xp0, it * TCH,
                                             h0c, Wih1b, bias1, xp1, it);
        lstm_rec2<<<32, 512, 0, stream>>>(xp0, xp1, Whh0b, Whh1b, h0c, h1l,
                                          hs0, cs0, hs1, cs1, it);
    }
    fc_k<<<256, 64, 0, stream>>>(h1l, fcw, fcb, out);
}

// Round 4
// 2372.121 us; speedup vs baseline: 1.1388x; 1.0977x over previous
//
#include <hip/hip_runtime.h>
#include <cstdint>
#include <cstddef>

// B=256, T=512, D=64, H=256, G=1024. Two-layer LSTM + FC.
// R9: single "mega" dispatch per pipeline step d = 0..18:
//   blocks   0- 15 : rec L0, chunk d-1 (reads xp0buf[(d-1)&1], writes h0cbuf[(d-1)&1])
//   blocks  16- 31 : rec L1, chunk d-3 (reads xp1buf[(d-3)&1], writes hlast at end)
//   blocks  32-287 : gemmA, xp0 for chunk d from x (f32, inline bf16 convert)
//   blocks 288-543 : gemmB, xp1 for chunk d-2 from h0cbuf[(d-2)&1]
// Every producer->consumer is cross-dispatch; within a dispatch writers and
// readers touch opposite parities of the double buffers (no intra-dispatch
// dependencies, no flags). Gemm blocks run on the 224 CUs the rec blocks
// don't use, so the former 17x~30us serial gemm dispatches vanish from the
// timeline. Rec math identical to R8 (W k-frags 0-1 LDS, 2-5 reg, 6-7
// streamed; lgkmcnt-only barrier; coalesced h0c store from LDS).
#define GATES 1024
#define SEQT  512
#define TCH   32
#define NCH   16
#define XPSTEP 262144           // elements per timestep in rec-order xp
#define XPCH  8388608           // elements per chunk xp buffer (16 MB)
#define H0CCH 2097152           // elements per chunk h0c buffer (4 MB)

using u16 = unsigned short;
using bf16x8 = __attribute__((ext_vector_type(8))) short;   // 8 bf16 = 4 VGPRs
using f32x4  = __attribute__((ext_vector_type(4))) float;

__device__ __forceinline__ float bf2f(u16 u) {
    union { float f; unsigned int i; } v; v.i = ((unsigned int)u) << 16; return v.f;
}
__device__ __forceinline__ u16 f2bf(float f) {
    union { float f; unsigned int i; } v; v.f = f;
    unsigned int r = v.i + 0x7FFFu + ((v.i >> 16) & 1u);   // RNE
    return (u16)(r >> 16);
}
// overflow-safe fast activations (v_exp + v_rcp, ~1 ulp)
__device__ __forceinline__ float sigm(float x) {
    return __builtin_amdgcn_rcpf(1.f + __expf(-x));
}
__device__ __forceinline__ float tanh_f(float x) {
    return 1.f - 2.f * __builtin_amdgcn_rcpf(1.f + __expf(2.f * x));
}

// ---------------- prep ----------------
__global__ void k_conv(const float* __restrict__ src, u16* __restrict__ dst, int n) {
    int i = blockIdx.x * 256 + threadIdx.x;
    if (i < n) dst[i] = f2bf(src[i]);
}
__global__ void k_bias(const float* __restrict__ a, const float* __restrict__ b,
                       float* __restrict__ o, int n) {
    int i = blockIdx.x * 256 + threadIdx.x;
    if (i < n) o[i] = a[i] + b[i];
}

// ---------------- mega: rec (32 blocks) + gemmA (256) + gemmB (256) --------
__global__ __attribute__((amdgpu_flat_work_group_size(512, 512),
                          amdgpu_waves_per_eu(2, 2))) void mega(
    const float* __restrict__ x,
    const u16* __restrict__ Wih0b, const u16* __restrict__ Whh0b,
    const u16* __restrict__ Wih1b, const u16* __restrict__ Whh1b,
    const float* __restrict__ bias0, const float* __restrict__ bias1,
    u16* __restrict__ xp0base, u16* __restrict__ xp1base,
    u16* __restrict__ h0cbase, float* __restrict__ hlast,
    u16* __restrict__ hs0, float* __restrict__ cs0,
    u16* __restrict__ hs1, float* __restrict__ cs1, int d)
{
    __shared__ __align__(16) u16 SMEM[73984];   // 147968 B, overlaid per role
    const int tid = threadIdx.x;

    if (blockIdx.x < 32) {
        // =================== rec ===================
        const int L   = blockIdx.x >> 4;
        const int blk = blockIdx.x & 15;
        const int chunk = L ? d - 3 : d - 1;
        if (chunk < 0 || chunk >= NCH) return;
        const u16* xp = (L ? xp1base : xp0base) + (size_t)(chunk & 1) * XPCH;
        const u16* W  = L ? Whh1b : Whh0b;
        u16*  hs = L ? hs1 : hs0;
        float* cs = L ? cs1 : cs0;
        u16* h0c = h0cbase + (size_t)(chunk & 1) * H0CCH;
        const int init = (chunk == 0);

        u16* WL = SMEM;                                   // 131072 B
        u16 (*hAp)[264] = (u16 (*)[264])(SMEM + 65536);   // [2*16][264]

        const int wave = tid >> 6, lane = tid & 63;
        const int ml   = lane & 15, q = lane >> 4;
        const int ub   = wave * 32;
        const int bb0  = blk * 16;

        // W fragment element offsets: frag f = gi*2+s -> gate rows
        int woff_[8];
        #pragma unroll
        for (int gi = 0; gi < 4; ++gi)
            #pragma unroll
            for (int s = 0; s < 2; ++s)
                woff_[gi * 2 + s] = (gi * 256 + ub + s * 16 + ml) * 256 + q * 8;

        // stage W k-frags 0-1 into LDS
        const int wlb = (wave * 1024 + lane) * 8;
        #pragma unroll
        for (int kf = 0; kf < 2; ++kf)
            #pragma unroll
            for (int f = 0; f < 8; ++f)
                *(bf16x8*)&WL[wlb + (kf * 8 + f) * 512] =
                    *(const bf16x8*)(W + woff_[f] + kf * 32);

        // W k-frags 2-5 persistent in registers
        bf16x8 wreg[4][8];
        #pragma unroll
        for (int kf = 2; kf < 6; ++kf)
            #pragma unroll
            for (int f = 0; f < 8; ++f)
                wreg[kf - 2][f] = *(const bf16x8*)(W + woff_[f] + kf * 32);

        float c_[8];
        if (init) {
            for (int i = tid; i < 16 * 264; i += 512) ((u16*)hAp)[i] = 0;
            #pragma unroll
            for (int i = 0; i < 8; ++i) c_[i] = 0.f;
        } else {
            int m = tid >> 5, j0 = (tid & 31) * 8;
            *(bf16x8*)&hAp[m][j0] = *(const bf16x8*)&hs[(size_t)(bb0 + m) * 256 + j0];
            #pragma unroll
            for (int s = 0; s < 2; ++s)
                #pragma unroll
                for (int r = 0; r < 4; ++r)
                    c_[s * 4 + r] = cs[(size_t)(bb0 + q * 4 + r) * 256 + ub + s * 16 + ml];
        }

        const u16* xpt = xp + ((size_t)blk * 512 + tid) * 32;
        const int m_st = tid >> 5;
        const int j_st = (tid & 31) * 8;

        __syncthreads();

        for (int t = 0; t < TCH; ++t) {
            const int br = t & 1, bw = br ^ 1;

            bf16x8 xv[4];
            #pragma unroll
            for (int gi = 0; gi < 4; ++gi)
                xv[gi] = *(const bf16x8*)(xpt + gi * 8);

            bf16x8 wstr[2][8];
            #pragma unroll
            for (int kf = 0; kf < 2; ++kf)
                #pragma unroll
                for (int f = 0; f < 8; ++f)
                    wstr[kf][f] = *(const bf16x8*)(W + woff_[f] + (6 + kf) * 32);

            f32x4 acc[4][2];
            #pragma unroll
            for (int gi = 0; gi < 4; ++gi)
                #pragma unroll
                for (int s = 0; s < 2; ++s)
                    acc[gi][s] = (f32x4)0.f;

            #pragma unroll
            for (int kf = 0; kf < 2; ++kf) {
                bf16x8 a = *(const bf16x8*)&hAp[br * 16 + ml][kf * 32 + q * 8];
                #pragma unroll
                for (int f = 0; f < 8; ++f) {
                    bf16x8 b = *(const bf16x8*)&WL[wlb + (kf * 8 + f) * 512];
                    acc[f >> 1][f & 1] = __builtin_amdgcn_mfma_f32_16x16x32_bf16(
                        a, b, acc[f >> 1][f & 1], 0, 0, 0);
                }
            }
            #pragma unroll
            for (int kf = 2; kf < 6; ++kf) {
                bf16x8 a = *(const bf16x8*)&hAp[br * 16 + ml][kf * 32 + q * 8];
                #pragma unroll
                for (int f = 0; f < 8; ++f)
                    acc[f >> 1][f & 1] = __builtin_amdgcn_mfma_f32_16x16x32_bf16(
                        a, wreg[kf - 2][f], acc[f >> 1][f & 1], 0, 0, 0);
            }
            #pragma unroll
            for (int kf = 6; kf < 8; ++kf) {
                bf16x8 a = *(const bf16x8*)&hAp[br * 16 + ml][kf * 32 + q * 8];
                #pragma unroll
                for (int f = 0; f < 8; ++f)
                    acc[f >> 1][f & 1] = __builtin_amdgcn_mfma_f32_16x16x32_bf16(
                        a, wstr[kf - 6][f], acc[f >> 1][f & 1], 0, 0, 0);
            }

            float gv[4][2][4];
            #pragma unroll
            for (int gi = 0; gi < 4; ++gi)
                #pragma unroll
                for (int s = 0; s < 2; ++s)
                    #pragma unroll
                    for (int r = 0; r < 4; ++r) {
                        float pre = acc[gi][s][r] + bf2f((u16)xv[gi][s * 4 + r]);
                        gv[gi][s][r] = (gi == 2) ? tanh_f(pre) : sigm(pre);
                    }

            #pragma unroll
            for (int s = 0; s < 2; ++s) {
                const int j = ub + s * 16 + ml;
                float hv[4];
                #pragma unroll
                for (int r = 0; r < 4; ++r) {
                    float cc = gv[1][s][r] * c_[s * 4 + r] + gv[0][s][r] * gv[2][s][r];
                    c_[s * 4 + r] = cc;
                    hv[r] = gv[3][s][r] * tanh_f(cc);
                }
                unsigned p01, p23;
                asm("v_cvt_pk_bf16_f32 %0, %1, %2" : "=v"(p01) : "v"(hv[0]), "v"(hv[1]));
                asm("v_cvt_pk_bf16_f32 %0, %1, %2" : "=v"(p23) : "v"(hv[2]), "v"(hv[3]));
                hAp[bw * 16 + q * 4 + 0][j] = (u16)p01;
                hAp[bw * 16 + q * 4 + 1][j] = (u16)(p01 >> 16);
                hAp[bw * 16 + q * 4 + 2][j] = (u16)p23;
                hAp[bw * 16 + q * 4 + 3][j] = (u16)(p23 >> 16);
                if (L == 1 && chunk == NCH - 1 && t == TCH - 1) {
                    #pragma unroll
                    for (int r = 0; r < 4; ++r)
                        hlast[(size_t)(bb0 + q * 4 + r) * 256 + j] = hv[r];
                }
            }
            xpt += XPSTEP;

            // publish h(t+1): only hA ds_writes gate the barrier
            asm volatile("s_waitcnt lgkmcnt(0)\n\ts_barrier" ::: "memory");

            if (L == 0)
                *(bf16x8*)&h0c[((size_t)t * 256 + bb0 + m_st) * 256 + j_st] =
                    *(const bf16x8*)&hAp[bw * 16 + m_st][j_st];
        }

        // persist state (TCH even -> final h is in buf 0)
        #pragma unroll
        for (int s = 0; s < 2; ++s)
            #pragma unroll
            for (int r = 0; r < 4; ++r)
                cs[(size_t)(bb0 + q * 4 + r) * 256 + ub + s * 16 + ml] = c_[s * 4 + r];
        {
            int m = tid >> 5, j0 = (tid & 31) * 8;
            *(bf16x8*)&hs[(size_t)(bb0 + m) * 256 + j0] = *(const bf16x8*)&hAp[m][j0];
        }
        return;
    }

    // =================== gemm (A: xp0 from x; B: xp1 from h0c) ===================
    const int role = (blockIdx.x < 288) ? 0 : 1;
    const int bid  = blockIdx.x - (role ? 288 : 32);
    const int chunk = role ? d - 2 : d;
    if (chunk < 0 || chunk >= NCH) return;

    const int K = role ? 256 : 64;
    const u16* Wp = role ? Wih1b : Wih0b;
    const float* bias = role ? bias1 : bias0;
    u16* out = (role ? xp1base : xp0base) + (size_t)(chunk & 1) * XPCH;
    const u16* A1 = h0cbase + (size_t)(chunk & 1) * H0CCH;   // role B source

    u16 (*As)[40] = (u16 (*)[40])SMEM;            // [128][40]
    u16 (*Bs)[40] = (u16 (*)[40])(SMEM + 5120);   // [256][40]

    const int mb = bid >> 2, nb = bid & 3;
    const int n0 = nb * 256;
    const int wave = tid >> 6, lane = tid & 63;
    const int wm = wave >> 2, wn = wave & 3;      // 2 x 4 wave grid -> 128x256 tile
    const int ml = lane & 15, q = lane >> 4;
    const int tloc = mb >> 1;
    const int bbas = (mb & 1) * 128;
    const int tt = role ? tloc : chunk * TCH + tloc;

    f32x4 acc[4][4];
    #pragma unroll
    for (int mi = 0; mi < 4; ++mi)
        #pragma unroll
        for (int ni = 0; ni < 4; ++ni)
            acc[mi][ni] = (f32x4)0.f;

    const int nk = K >> 5;
    for (int kt = 0; kt < nk; ++kt) {
        __syncthreads();
        {
            int row = tid >> 2, kb = tid & 3;
            if (role) {
                *(uint4*)&As[row][kb * 8] = *(const uint4*)(
                    A1 + (size_t)tt * 65536 + (size_t)(bbas + row) * 256 + kt * 32 + kb * 8);
            } else {
                const float* xs = x + (size_t)(bbas + row) * 32768 + (size_t)tt * 64
                                    + kt * 32 + kb * 8;
                float4 fa = *(const float4*)xs;
                float4 fb = *(const float4*)(xs + 4);
                uint4 v;
                v.x = f2bf(fa.x) | ((unsigned)f2bf(fa.y) << 16);
                v.y = f2bf(fa.z) | ((unsigned)f2bf(fa.w) << 16);
                v.z = f2bf(fb.x) | ((unsigned)f2bf(fb.y) << 16);
                v.w = f2bf(fb.z) | ((unsigned)f2bf(fb.w) << 16);
                *(uint4*)&As[row][kb * 8] = v;
            }
            #pragma unroll
            for (int i = 0; i < 2; ++i) {
                int c2 = tid + i * 512, r2 = c2 >> 2, k2 = c2 & 3;
                *(uint4*)&Bs[r2][k2 * 8] = *(const uint4*)(
                    Wp + (size_t)(n0 + r2) * K + kt * 32 + k2 * 8);
            }
        }
        __syncthreads();
        bf16x8 af[4], bfr[4];
        #pragma unroll
        for (int mi = 0; mi < 4; ++mi)
            af[mi] = *(const bf16x8*)&As[wm * 64 + mi * 16 + ml][q * 8];
        #pragma unroll
        for (int ni = 0; ni < 4; ++ni)
            bfr[ni] = *(const bf16x8*)&Bs[wn * 64 + ni * 16 + ml][q * 8];
        #pragma unroll
        for (int mi = 0; mi < 4; ++mi)
            #pragma unroll
            for (int ni = 0; ni < 4; ++ni)
                acc[mi][ni] = __builtin_amdgcn_mfma_f32_16x16x32_bf16(
                    af[mi], bfr[ni], acc[mi][ni], 0, 0, 0);
    }

    #pragma unroll
    for (int ni = 0; ni < 4; ++ni) {
        int gc = n0 + wn * 64 + ni * 16 + ml;
        int gi = gc >> 8, u = gc & 255;
        int w = u >> 5, s = (u >> 4) & 1, mlr = u & 15;
        float bv = bias[gc];
        #pragma unroll
        for (int mi = 0; mi < 4; ++mi) {
            int b0r = bbas + wm * 64 + mi * 16 + q * 4;
            #pragma unroll
            for (int rr = 0; rr < 4; ++rr) {
                int bb = b0r + rr;
                int blk2 = bb >> 4, qr = (bb >> 2) & 3, r_r = bb & 3;
                size_t el = ((size_t)((tloc * 16 + blk2) * 512 + w * 64 + qr * 16 + mlr)) * 32
                            + gi * 8 + s * 4 + r_r;
                out[el] = f2bf(acc[mi][ni][rr] + bv);
            }
        }
    }
}

// ---------------- FC head ----------------
__global__ void fc_k(const float* __restrict__ h, const float* __restrict__ w,
                     const float* __restrict__ b, float* __restrict__ out)
{
    int bb = blockIdx.x, lane = threadIdx.x;
    float s = 0.f;
    for (int j = lane; j < 256; j += 64) s += h[bb * 256 + j] * w[j];
    #pragma unroll
    for (int off = 32; off > 0; off >>= 1) s += __shfl_down(s, off);
    if (lane == 0) out[bb] = s + b[0];
}

extern "C" void kernel_launch(void* const* d_in, const int* in_sizes, int n_in,
                              void* d_out, int out_size, void* d_ws, size_t ws_size,
                              hipStream_t stream)
{
    const float* x    = (const float*)d_in[0];
    const float* Wih0 = (const float*)d_in[1];
    const float* Whh0 = (const float*)d_in[2];
    const float* bih0 = (const float*)d_in[3];
    const float* bhh0 = (const float*)d_in[4];
    const float* Wih1 = (const float*)d_in[5];
    const float* Whh1 = (const float*)d_in[6];
    const float* bih1 = (const float*)d_in[7];
    const float* bhh1 = (const float*)d_in[8];
    const float* fcw  = (const float*)d_in[9];
    const float* fcb  = (const float*)d_in[10];
    float* out = (float*)d_out;

    // workspace layout, total ~74.6 MB
    char* ws = (char*)d_ws;
    u16*   xp0b  = (u16*)(ws);                  // 33554432  (2 chunks)
    u16*   xp1b  = (u16*)(ws + 33554432);       // 33554432  (2 chunks)
    u16*   h0cb  = (u16*)(ws + 67108864);       //  8388608  (2 chunks)
    u16*   Wih0b = (u16*)(ws + 75497472);       //   131072
    u16*   Whh0b = (u16*)(ws + 75628544);       //   524288
    u16*   Wih1b = (u16*)(ws + 76152832);       //   524288
    u16*   Whh1b = (u16*)(ws + 76677120);       //   524288
    float* bias0 = (float*)(ws + 77201408);     //     4096
    float* bias1 = (float*)(ws + 77205504);     //     4096
    u16*   hs0   = (u16*)(ws + 77209600);       //   131072
    float* cs0   = (float*)(ws + 77340672);     //   262144
    u16*   hs1   = (u16*)(ws + 77602816);       //   131072
    float* cs1   = (float*)(ws + 77733888);     //   262144
    float* h1l   = (float*)(ws + 77996032);     //   262144

    k_conv<<<256,  256, 0, stream>>>(Wih0, Wih0b, 65536);
    k_conv<<<1024, 256, 0, stream>>>(Whh0, Whh0b, 262144);
    k_conv<<<1024, 256, 0, stream>>>(Wih1, Wih1b, 262144);
    k_conv<<<1024, 256, 0, stream>>>(Whh1, Whh1b, 262144);
    k_bias<<<4, 256, 0, stream>>>(bih0, bhh0, bias0, 1024);
    k_bias<<<4, 256, 0, stream>>>(bih1, bhh1, bias1, 1024);

    for (int d = 0; d <= NCH + 2; ++d)   // d = 0..18
        mega<<<544, 512, 0, stream>>>(x, Wih0b, Whh0b, Wih1b, Whh1b,
                                      bias0, bias1, xp0b, xp1b, h0cb, h1l,
                                      hs0, cs0, hs1, cs1, d);
    fc_k<<<256, 64, 0, stream>>>(h1l, fcw, fcb, out);
}

// Round 5
// 2355.783 us; speedup vs baseline: 1.1467x; 1.0069x over previous
//
#include <hip/hip_runtime.h>
#include <cstdint>
#include <cstddef>

// B=256, T=512, D=64, H=256, G=1024. Two-layer LSTM + FC.
// R9: single "mega" dispatch per pipeline step d = 0..18:
//   blocks   0- 15 : rec L0, chunk d-1   blocks  16- 31 : rec L1, chunk d-3
//   blocks  32-287 : gemmA xp0(d) from x  blocks 288-543 : gemmB xp1(d-2) from h0c
// R10: rec per-step software pipeline. The kf6-7 W stream (128 KB/block/step
// from L2, ~2900 cyc of VMEM drain) was issued at step top and consumed
// mid-step -> on the critical path. Now wstr/xv are PREFETCHED one step
// ahead: reloaded immediately after their consumers (kf6-7 MFMA /
// activations), giving a full step of slack to drain under MFMA+trans.
// gv[] folded into the cell loop to cut ~32 live VGPRs (spill guard).
#define GATES 1024
#define SEQT  512
#define TCH   32
#define NCH   16
#define XPSTEP 262144           // elements per timestep in rec-order xp
#define XPCH  8388608           // elements per chunk xp buffer (16 MB)
#define H0CCH 2097152           // elements per chunk h0c buffer (4 MB)

using u16 = unsigned short;
using bf16x8 = __attribute__((ext_vector_type(8))) short;   // 8 bf16 = 4 VGPRs
using f32x4  = __attribute__((ext_vector_type(4))) float;

__device__ __forceinline__ float bf2f(u16 u) {
    union { float f; unsigned int i; } v; v.i = ((unsigned int)u) << 16; return v.f;
}
__device__ __forceinline__ u16 f2bf(float f) {
    union { float f; unsigned int i; } v; v.f = f;
    unsigned int r = v.i + 0x7FFFu + ((v.i >> 16) & 1u);   // RNE
    return (u16)(r >> 16);
}
// overflow-safe fast activations (v_exp + v_rcp, ~1 ulp)
__device__ __forceinline__ float sigm(float x) {
    return __builtin_amdgcn_rcpf(1.f + __expf(-x));
}
__device__ __forceinline__ float tanh_f(float x) {
    return 1.f - 2.f * __builtin_amdgcn_rcpf(1.f + __expf(2.f * x));
}

// ---------------- prep ----------------
__global__ void k_conv(const float* __restrict__ src, u16* __restrict__ dst, int n) {
    int i = blockIdx.x * 256 + threadIdx.x;
    if (i < n) dst[i] = f2bf(src[i]);
}
__global__ void k_bias(const float* __restrict__ a, const float* __restrict__ b,
                       float* __restrict__ o, int n) {
    int i = blockIdx.x * 256 + threadIdx.x;
    if (i < n) o[i] = a[i] + b[i];
}

// ---------------- mega: rec (32 blocks) + gemmA (256) + gemmB (256) --------
__global__ __attribute__((amdgpu_flat_work_group_size(512, 512),
                          amdgpu_waves_per_eu(2, 2))) void mega(
    const float* __restrict__ x,
    const u16* __restrict__ Wih0b, const u16* __restrict__ Whh0b,
    const u16* __restrict__ Wih1b, const u16* __restrict__ Whh1b,
    const float* __restrict__ bias0, const float* __restrict__ bias1,
    u16* __restrict__ xp0base, u16* __restrict__ xp1base,
    u16* __restrict__ h0cbase, float* __restrict__ hlast,
    u16* __restrict__ hs0, float* __restrict__ cs0,
    u16* __restrict__ hs1, float* __restrict__ cs1, int d)
{
    __shared__ __align__(16) u16 SMEM[73984];   // 147968 B, overlaid per role
    const int tid = threadIdx.x;

    if (blockIdx.x < 32) {
        // =================== rec ===================
        const int L   = blockIdx.x >> 4;
        const int blk = blockIdx.x & 15;
        const int chunk = L ? d - 3 : d - 1;
        if (chunk < 0 || chunk >= NCH) return;
        const u16* xp = (L ? xp1base : xp0base) + (size_t)(chunk & 1) * XPCH;
        const u16* W  = L ? Whh1b : Whh0b;
        u16*  hs = L ? hs1 : hs0;
        float* cs = L ? cs1 : cs0;
        u16* h0c = h0cbase + (size_t)(chunk & 1) * H0CCH;
        const int init = (chunk == 0);

        u16* WL = SMEM;                                   // 131072 B
        u16 (*hAp)[264] = (u16 (*)[264])(SMEM + 65536);   // [2*16][264]

        const int wave = tid >> 6, lane = tid & 63;
        const int ml   = lane & 15, q = lane >> 4;
        const int ub   = wave * 32;
        const int bb0  = blk * 16;

        // W fragment element offsets: frag f = gi*2+s -> gate rows
        int woff_[8];
        #pragma unroll
        for (int gi = 0; gi < 4; ++gi)
            #pragma unroll
            for (int s = 0; s < 2; ++s)
                woff_[gi * 2 + s] = (gi * 256 + ub + s * 16 + ml) * 256 + q * 8;

        // stage W k-frags 0-1 into LDS
        const int wlb = (wave * 1024 + lane) * 8;
        #pragma unroll
        for (int kf = 0; kf < 2; ++kf)
            #pragma unroll
            for (int f = 0; f < 8; ++f)
                *(bf16x8*)&WL[wlb + (kf * 8 + f) * 512] =
                    *(const bf16x8*)(W + woff_[f] + kf * 32);

        // W k-frags 2-5 persistent in registers
        bf16x8 wreg[4][8];
        #pragma unroll
        for (int kf = 2; kf < 6; ++kf)
            #pragma unroll
            for (int f = 0; f < 8; ++f)
                wreg[kf - 2][f] = *(const bf16x8*)(W + woff_[f] + kf * 32);

        float c_[8];
        if (init) {
            for (int i = tid; i < 16 * 264; i += 512) ((u16*)hAp)[i] = 0;
            #pragma unroll
            for (int i = 0; i < 8; ++i) c_[i] = 0.f;
        } else {
            int m = tid >> 5, j0 = (tid & 31) * 8;
            *(bf16x8*)&hAp[m][j0] = *(const bf16x8*)&hs[(size_t)(bb0 + m) * 256 + j0];
            #pragma unroll
            for (int s = 0; s < 2; ++s)
                #pragma unroll
                for (int r = 0; r < 4; ++r)
                    c_[s * 4 + r] = cs[(size_t)(bb0 + q * 4 + r) * 256 + ub + s * 16 + ml];
        }

        const u16* xpt = xp + ((size_t)blk * 512 + tid) * 32;
        const int m_st = tid >> 5;
        const int j_st = (tid & 31) * 8;

        __syncthreads();

        // software-pipeline prologue: xv(0) and wstr prefetched before loop
        bf16x8 xv[4];
        #pragma unroll
        for (int gi = 0; gi < 4; ++gi)
            xv[gi] = *(const bf16x8*)(xpt + gi * 8);
        bf16x8 wstr[2][8];
        #pragma unroll
        for (int kf = 0; kf < 2; ++kf)
            #pragma unroll
            for (int f = 0; f < 8; ++f)
                wstr[kf][f] = *(const bf16x8*)(W + woff_[f] + (6 + kf) * 32);

        for (int t = 0; t < TCH; ++t) {
            const int br = t & 1, bw = br ^ 1;

            f32x4 acc[4][2];
            #pragma unroll
            for (int gi = 0; gi < 4; ++gi)
                #pragma unroll
                for (int s = 0; s < 2; ++s)
                    acc[gi][s] = (f32x4)0.f;

            #pragma unroll
            for (int kf = 0; kf < 2; ++kf) {
                bf16x8 a = *(const bf16x8*)&hAp[br * 16 + ml][kf * 32 + q * 8];
                #pragma unroll
                for (int f = 0; f < 8; ++f) {
                    bf16x8 b = *(const bf16x8*)&WL[wlb + (kf * 8 + f) * 512];
                    acc[f >> 1][f & 1] = __builtin_amdgcn_mfma_f32_16x16x32_bf16(
                        a, b, acc[f >> 1][f & 1], 0, 0, 0);
                }
            }
            #pragma unroll
            for (int kf = 2; kf < 6; ++kf) {
                bf16x8 a = *(const bf16x8*)&hAp[br * 16 + ml][kf * 32 + q * 8];
                #pragma unroll
                for (int f = 0; f < 8; ++f)
                    acc[f >> 1][f & 1] = __builtin_amdgcn_mfma_f32_16x16x32_bf16(
                        a, wreg[kf - 2][f], acc[f >> 1][f & 1], 0, 0, 0);
            }
            // kf6-7: wstr was prefetched a full step ago -> no VMEM stall here
            #pragma unroll
            for (int kf = 6; kf < 8; ++kf) {
                bf16x8 a = *(const bf16x8*)&hAp[br * 16 + ml][kf * 32 + q * 8];
                #pragma unroll
                for (int f = 0; f < 8; ++f)
                    acc[f >> 1][f & 1] = __builtin_amdgcn_mfma_f32_16x16x32_bf16(
                        a, wstr[kf - 6][f], acc[f >> 1][f & 1], 0, 0, 0);
            }
            // reload wstr for t+1 (WAR on the MFMAs above orders issue here;
            // 128 KB/block of L2 traffic drains under the rest of this step)
            #pragma unroll
            for (int kf = 0; kf < 2; ++kf)
                #pragma unroll
                for (int f = 0; f < 8; ++f)
                    wstr[kf][f] = *(const bf16x8*)(W + woff_[f] + (6 + kf) * 32);

            // activations + cell update (xv prefetched a full step ago)
            #pragma unroll
            for (int s = 0; s < 2; ++s) {
                const int j = ub + s * 16 + ml;
                float hv[4];
                #pragma unroll
                for (int r = 0; r < 4; ++r) {
                    float ig = sigm(acc[0][s][r] + bf2f((u16)xv[0][s * 4 + r]));
                    float fg = sigm(acc[1][s][r] + bf2f((u16)xv[1][s * 4 + r]));
                    float gg = tanh_f(acc[2][s][r] + bf2f((u16)xv[2][s * 4 + r]));
                    float og = sigm(acc[3][s][r] + bf2f((u16)xv[3][s * 4 + r]));
                    float cc = fg * c_[s * 4 + r] + ig * gg;
                    c_[s * 4 + r] = cc;
                    hv[r] = og * tanh_f(cc);
                }
                unsigned p01, p23;
                asm("v_cvt_pk_bf16_f32 %0, %1, %2" : "=v"(p01) : "v"(hv[0]), "v"(hv[1]));
                asm("v_cvt_pk_bf16_f32 %0, %1, %2" : "=v"(p23) : "v"(hv[2]), "v"(hv[3]));
                hAp[bw * 16 + q * 4 + 0][j] = (u16)p01;
                hAp[bw * 16 + q * 4 + 1][j] = (u16)(p01 >> 16);
                hAp[bw * 16 + q * 4 + 2][j] = (u16)p23;
                hAp[bw * 16 + q * 4 + 3][j] = (u16)(p23 >> 16);
                if (L == 1 && chunk == NCH - 1 && t == TCH - 1) {
                    #pragma unroll
                    for (int r = 0; r < 4; ++r)
                        hlast[(size_t)(bb0 + q * 4 + r) * 256 + j] = hv[r];
                }
            }
            // reload xv for t+1 (t=TCH-1 reads one step past the chunk --
            // stays inside the workspace, values never consumed)
            xpt += XPSTEP;
            #pragma unroll
            for (int gi = 0; gi < 4; ++gi)
                xv[gi] = *(const bf16x8*)(xpt + gi * 8);

            // publish h(t+1): only hA ds_writes gate the barrier
            asm volatile("s_waitcnt lgkmcnt(0)\n\ts_barrier" ::: "memory");

            if (L == 0)
                *(bf16x8*)&h0c[((size_t)t * 256 + bb0 + m_st) * 256 + j_st] =
                    *(const bf16x8*)&hAp[bw * 16 + m_st][j_st];
        }

        // persist state (TCH even -> final h is in buf 0)
        #pragma unroll
        for (int s = 0; s < 2; ++s)
            #pragma unroll
            for (int r = 0; r < 4; ++r)
                cs[(size_t)(bb0 + q * 4 + r) * 256 + ub + s * 16 + ml] = c_[s * 4 + r];
        {
            int m = tid >> 5, j0 = (tid & 31) * 8;
            *(bf16x8*)&hs[(size_t)(bb0 + m) * 256 + j0] = *(const bf16x8*)&hAp[m][j0];
        }
        return;
    }

    // =================== gemm (A: xp0 from x; B: xp1 from h0c) ===================
    const int role = (blockIdx.x < 288) ? 0 : 1;
    const int bid  = blockIdx.x - (role ? 288 : 32);
    const int chunk = role ? d - 2 : d;
    if (chunk < 0 || chunk >= NCH) return;

    const int K = role ? 256 : 64;
    const u16* Wp = role ? Wih1b : Wih0b;
    const float* bias = role ? bias1 : bias0;
    u16* out = (role ? xp1base : xp0base) + (size_t)(chunk & 1) * XPCH;
    const u16* A1 = h0cbase + (size_t)(chunk & 1) * H0CCH;   // role B source

    u16 (*As)[40] = (u16 (*)[40])SMEM;            // [128][40]
    u16 (*Bs)[40] = (u16 (*)[40])(SMEM + 5120);   // [256][40]

    const int mb = bid >> 2, nb = bid & 3;
    const int n0 = nb * 256;
    const int wave = tid >> 6, lane = tid & 63;
    const int wm = wave >> 2, wn = wave & 3;      // 2 x 4 wave grid -> 128x256 tile
    const int ml = lane & 15, q = lane >> 4;
    const int tloc = mb >> 1;
    const int bbas = (mb & 1) * 128;
    const int tt = role ? tloc : chunk * TCH + tloc;

    f32x4 acc[4][4];
    #pragma unroll
    for (int mi = 0; mi < 4; ++mi)
        #pragma unroll
        for (int ni = 0; ni < 4; ++ni)
            acc[mi][ni] = (f32x4)0.f;

    const int nk = K >> 5;
    for (int kt = 0; kt < nk; ++kt) {
        __syncthreads();
        {
            int row = tid >> 2, kb = tid & 3;
            if (role) {
                *(uint4*)&As[row][kb * 8] = *(const uint4*)(
                    A1 + (size_t)tt * 65536 + (size_t)(bbas + row) * 256 + kt * 32 + kb * 8);
            } else {
                const float* xs = x + (size_t)(bbas + row) * 32768 + (size_t)tt * 64
                                    + kt * 32 + kb * 8;
                float4 fa = *(const float4*)xs;
                float4 fb = *(const float4*)(xs + 4);
                uint4 v;
                v.x = f2bf(fa.x) | ((unsigned)f2bf(fa.y) << 16);
                v.y = f2bf(fa.z) | ((unsigned)f2bf(fa.w) << 16);
                v.z = f2bf(fb.x) | ((unsigned)f2bf(fb.y) << 16);
                v.w = f2bf(fb.z) | ((unsigned)f2bf(fb.w) << 16);
                *(uint4*)&As[row][kb * 8] = v;
            }
            #pragma unroll
            for (int i = 0; i < 2; ++i) {
                int c2 = tid + i * 512, r2 = c2 >> 2, k2 = c2 & 3;
                *(uint4*)&Bs[r2][k2 * 8] = *(const uint4*)(
                    Wp + (size_t)(n0 + r2) * K + kt * 32 + k2 * 8);
            }
        }
        __syncthreads();
        bf16x8 af[4], bfr[4];
        #pragma unroll
        for (int mi = 0; mi < 4; ++mi)
            af[mi] = *(const bf16x8*)&As[wm * 64 + mi * 16 + ml][q * 8];
        #pragma unroll
        for (int ni = 0; ni < 4; ++ni)
            bfr[ni] = *(const bf16x8*)&Bs[wn * 64 + ni * 16 + ml][q * 8];
        #pragma unroll
        for (int mi = 0; mi < 4; ++mi)
            #pragma unroll
            for (int ni = 0; ni < 4; ++ni)
                acc[mi][ni] = __builtin_amdgcn_mfma_f32_16x16x32_bf16(
                    af[mi], bfr[ni], acc[mi][ni], 0, 0, 0);
    }

    #pragma unroll
    for (int ni = 0; ni < 4; ++ni) {
        int gc = n0 + wn * 64 + ni * 16 + ml;
        int gi = gc >> 8, u = gc & 255;
        int w = u >> 5, s = (u >> 4) & 1, mlr = u & 15;
        float bv = bias[gc];
        #pragma unroll
        for (int mi = 0; mi < 4; ++mi) {
            int b0r = bbas + wm * 64 + mi * 16 + q * 4;
            #pragma unroll
            for (int rr = 0; rr < 4; ++rr) {
                int bb = b0r + rr;
                int blk2 = bb >> 4, qr = (bb >> 2) & 3, r_r = bb & 3;
                size_t el = ((size_t)((tloc * 16 + blk2) * 512 + w * 64 + qr * 16 + mlr)) * 32
                            + gi * 8 + s * 4 + r_r;
                out[el] = f2bf(acc[mi][ni][rr] + bv);
            }
        }
    }
}

// ---------------- FC head ----------------
__global__ void fc_k(const float* __restrict__ h, const float* __restrict__ w,
                     const float* __restrict__ b, float* __restrict__ out)
{
    int bb = blockIdx.x, lane = threadIdx.x;
    float s = 0.f;
    for (int j = lane; j < 256; j += 64) s += h[bb * 256 + j] * w[j];
    #pragma unroll
    for (int off = 32; off > 0; off >>= 1) s += __shfl_down(s, off);
    if (lane == 0) out[bb] = s + b[0];
}

extern "C" void kernel_launch(void* const* d_in, const int* in_sizes, int n_in,
                              void* d_out, int out_size, void* d_ws, size_t ws_size,
                              hipStream_t stream)
{
    const float* x    = (const float*)d_in[0];
    const float* Wih0 = (const float*)d_in[1];
    const float* Whh0 = (const float*)d_in[2];
    const float* bih0 = (const float*)d_in[3];
    const float* bhh0 = (const float*)d_in[4];
    const float* Wih1 = (const float*)d_in[5];
    const float* Whh1 = (const float*)d_in[6];
    const float* bih1 = (const float*)d_in[7];
    const float* bhh1 = (const float*)d_in[8];
    const float* fcw  = (const float*)d_in[9];
    const float* fcb  = (const float*)d_in[10];
    float* out = (float*)d_out;

    // workspace layout, total ~74.6 MB
    char* ws = (char*)d_ws;
    u16*   xp0b  = (u16*)(ws);                  // 33554432  (2 chunks)
    u16*   xp1b  = (u16*)(ws + 33554432);       // 33554432  (2 chunks)
    u16*   h0cb  = (u16*)(ws + 67108864);       //  8388608  (2 chunks)
    u16*   Wih0b = (u16*)(ws + 75497472);       //   131072
    u16*   Whh0b = (u16*)(ws + 75628544);       //   524288
    u16*   Wih1b = (u16*)(ws + 76152832);       //   524288
    u16*   Whh1b = (u16*)(ws + 76677120);       //   524288
    float* bias0 = (float*)(ws + 77201408);     //     4096
    float* bias1 = (float*)(ws + 77205504);     //     4096
    u16*   hs0   = (u16*)(ws + 77209600);       //   131072
    float* cs0   = (float*)(ws + 77340672);     //   262144
    u16*   hs1   = (u16*)(ws + 77602816);       //   131072
    float* cs1   = (float*)(ws + 77733888);     //   262144
    float* h1l   = (float*)(ws + 77996032);     //   262144

    k_conv<<<256,  256, 0, stream>>>(Wih0, Wih0b, 65536);
    k_conv<<<1024, 256, 0, stream>>>(Whh0, Whh0b, 262144);
    k_conv<<<1024, 256, 0, stream>>>(Wih1, Wih1b, 262144);
    k_conv<<<1024, 256, 0, stream>>>(Whh1, Whh1b, 262144);
    k_bias<<<4, 256, 0, stream>>>(bih0, bhh0, bias0, 1024);
    k_bias<<<4, 256, 0, stream>>>(bih1, bhh1, bias1, 1024);

    for (int d = 0; d <= NCH + 2; ++d)   // d = 0..18
        mega<<<544, 512, 0, stream>>>(x, Wih0b, Whh0b, Wih1b, Whh1b,
                                      bias0, bias1, xp0b, xp1b, h0cb, h1l,
                                      hs0, cs0, hs1, cs1, d);
    fc_k<<<256, 64, 0, stream>>>(h1l, fcw, fcb, out);
}

// Round 6
// 2131.451 us; speedup vs baseline: 1.2673x; 1.1052x over previous
//
#include <hip/hip_runtime.h>
#include <cstdint>
#include <cstddef>

// B=256, T=512, D=64, H=256, G=1024. Two-layer LSTM + FC.
// R9: single "mega" dispatch per pipeline step d = 0..18:
//   blocks   0- 15 : rec L0, chunk d-1   blocks  16- 31 : rec L1, chunk d-3
//   blocks  32-287 : gemmA xp0(d) from x  blocks 288-543 : gemmB xp1(d-2) from h0c
// R10: wstr/xv prefetched one step ahead (neutral -> compiler already did it).
// R11: kill address divergence. The old W/xp layouts put consecutive ROWS
// (stride 512B/64B) in consecutive lanes: every wave VMEM inst touched 64
// distinct cache lines (4x the TA/L2 request cost). Now:
//  - W_hh pre-shuffled once (k_wshuf) into frag-order Wf[wave][kf][f][lane][8]
//    -> WL-stage / wreg / wstr reads are contiguous 1KB per wave inst.
//  - xp layout [t][blk][gi][tid][8] -> each xv load contiguous 1KB per wave.
//    gemm epilogue writes the new index (4 stores/thread now 8B-contiguous).
#define GATES 1024
#define SEQT  512
#define TCH   32
#define NCH   16
#define XPSTEP 262144           // elements per timestep in rec-order xp
#define XPCH  8388608           // elements per chunk xp buffer (16 MB)
#define H0CCH 2097152           // elements per chunk h0c buffer (4 MB)

using u16 = unsigned short;
using bf16x8 = __attribute__((ext_vector_type(8))) short;   // 8 bf16 = 4 VGPRs
using f32x4  = __attribute__((ext_vector_type(4))) float;

__device__ __forceinline__ float bf2f(u16 u) {
    union { float f; unsigned int i; } v; v.i = ((unsigned int)u) << 16; return v.f;
}
__device__ __forceinline__ u16 f2bf(float f) {
    union { float f; unsigned int i; } v; v.f = f;
    unsigned int r = v.i + 0x7FFFu + ((v.i >> 16) & 1u);   // RNE
    return (u16)(r >> 16);
}
// overflow-safe fast activations (v_exp + v_rcp, ~1 ulp)
__device__ __forceinline__ float sigm(float x) {
    return __builtin_amdgcn_rcpf(1.f + __expf(-x));
}
__device__ __forceinline__ float tanh_f(float x) {
    return 1.f - 2.f * __builtin_amdgcn_rcpf(1.f + __expf(2.f * x));
}

// ---------------- prep ----------------
__global__ void k_conv(const float* __restrict__ src, u16* __restrict__ dst, int n) {
    int i = blockIdx.x * 256 + threadIdx.x;
    if (i < n) dst[i] = f2bf(src[i]);
}
__global__ void k_bias(const float* __restrict__ a, const float* __restrict__ b,
                       float* __restrict__ o, int n) {
    int i = blockIdx.x * 256 + threadIdx.x;
    if (i < n) o[i] = a[i] + b[i];
}
// W_hh [1024][256] -> frag-order Wf[((wave*8+kf)*8+f)*512 + lane*8 + e]
// row = gi*256 + wave*32 + s*16 + ml (gi=f>>1, s=f&1, ml=lane&15)
// col = kf*32 + (lane>>4)*8 + e
__global__ void k_wshuf(const u16* __restrict__ src, u16* __restrict__ dst) {
    int idx = blockIdx.x;                 // 512 blocks = (wave*8+kf)*8+f
    int f = idx & 7, kf = (idx >> 3) & 7, wave = idx >> 6;
    int lane = threadIdx.x;               // 64 threads
    int ml = lane & 15, q = lane >> 4;
    int row = (f >> 1) * 256 + wave * 32 + (f & 1) * 16 + ml;
    int col = kf * 32 + q * 8;
    *(bf16x8*)&dst[(size_t)idx * 512 + lane * 8] =
        *(const bf16x8*)&src[(size_t)row * 256 + col];
}

// ---------------- mega: rec (32 blocks) + gemmA (256) + gemmB (256) --------
__global__ __attribute__((amdgpu_flat_work_group_size(512, 512),
                          amdgpu_waves_per_eu(2, 2))) void mega(
    const float* __restrict__ x,
    const u16* __restrict__ Wih0b, const u16* __restrict__ Whh0f,
    const u16* __restrict__ Wih1b, const u16* __restrict__ Whh1f,
    const float* __restrict__ bias0, const float* __restrict__ bias1,
    u16* __restrict__ xp0base, u16* __restrict__ xp1base,
    u16* __restrict__ h0cbase, float* __restrict__ hlast,
    u16* __restrict__ hs0, float* __restrict__ cs0,
    u16* __restrict__ hs1, float* __restrict__ cs1, int d)
{
    __shared__ __align__(16) u16 SMEM[73984];   // 147968 B, overlaid per role
    const int tid = threadIdx.x;

    if (blockIdx.x < 32) {
        // =================== rec ===================
        const int L   = blockIdx.x >> 4;
        const int blk = blockIdx.x & 15;
        const int chunk = L ? d - 3 : d - 1;
        if (chunk < 0 || chunk >= NCH) return;
        const u16* xp = (L ? xp1base : xp0base) + (size_t)(chunk & 1) * XPCH;
        const u16* Wf = L ? Whh1f : Whh0f;
        u16*  hs = L ? hs1 : hs0;
        float* cs = L ? cs1 : cs0;
        u16* h0c = h0cbase + (size_t)(chunk & 1) * H0CCH;
        const int init = (chunk == 0);

        u16* WL = SMEM;                                   // 131072 B
        u16 (*hAp)[264] = (u16 (*)[264])(SMEM + 65536);   // [2*16][264]

        const int wave = tid >> 6, lane = tid & 63;
        const int ml   = lane & 15, q = lane >> 4;
        const int ub   = wave * 32;
        const int bb0  = blk * 16;

        // frag-order W base for this wave/lane: all accesses lane-contiguous
        const u16* wfb = Wf + (size_t)wave * 32768 + lane * 8;

        // stage W k-frags 0-1 into LDS (contiguous 1KB per wave inst)
        const int wlb = (wave * 1024 + lane) * 8;
        #pragma unroll
        for (int kf = 0; kf < 2; ++kf)
            #pragma unroll
            for (int f = 0; f < 8; ++f)
                *(bf16x8*)&WL[wlb + (kf * 8 + f) * 512] =
                    *(const bf16x8*)(wfb + (kf * 8 + f) * 512);

        // W k-frags 2-5 persistent in registers
        bf16x8 wreg[4][8];
        #pragma unroll
        for (int kf = 2; kf < 6; ++kf)
            #pragma unroll
            for (int f = 0; f < 8; ++f)
                wreg[kf - 2][f] = *(const bf16x8*)(wfb + (kf * 8 + f) * 512);

        float c_[8];
        if (init) {
            for (int i = tid; i < 16 * 264; i += 512) ((u16*)hAp)[i] = 0;
            #pragma unroll
            for (int i = 0; i < 8; ++i) c_[i] = 0.f;
        } else {
            int m = tid >> 5, j0 = (tid & 31) * 8;
            *(bf16x8*)&hAp[m][j0] = *(const bf16x8*)&hs[(size_t)(bb0 + m) * 256 + j0];
            #pragma unroll
            for (int s = 0; s < 2; ++s)
                #pragma unroll
                for (int r = 0; r < 4; ++r)
                    c_[s * 4 + r] = cs[(size_t)(bb0 + q * 4 + r) * 256 + ub + s * 16 + ml];
        }

        // xp: [t16+blk][gi][tid][8] -> per-gi contiguous 1KB per wave inst
        const u16* xpt = xp + (size_t)blk * 16384 + (size_t)tid * 8;
        const int m_st = tid >> 5;
        const int j_st = (tid & 31) * 8;

        __syncthreads();

        // software-pipeline prologue: xv(0) and wstr prefetched before loop
        bf16x8 xv[4];
        #pragma unroll
        for (int gi = 0; gi < 4; ++gi)
            xv[gi] = *(const bf16x8*)(xpt + gi * 4096);
        bf16x8 wstr[2][8];
        #pragma unroll
        for (int kf = 0; kf < 2; ++kf)
            #pragma unroll
            for (int f = 0; f < 8; ++f)
                wstr[kf][f] = *(const bf16x8*)(wfb + ((6 + kf) * 8 + f) * 512);

        for (int t = 0; t < TCH; ++t) {
            const int br = t & 1, bw = br ^ 1;

            f32x4 acc[4][2];
            #pragma unroll
            for (int gi = 0; gi < 4; ++gi)
                #pragma unroll
                for (int s = 0; s < 2; ++s)
                    acc[gi][s] = (f32x4)0.f;

            #pragma unroll
            for (int kf = 0; kf < 2; ++kf) {
                bf16x8 a = *(const bf16x8*)&hAp[br * 16 + ml][kf * 32 + q * 8];
                #pragma unroll
                for (int f = 0; f < 8; ++f) {
                    bf16x8 b = *(const bf16x8*)&WL[wlb + (kf * 8 + f) * 512];
                    acc[f >> 1][f & 1] = __builtin_amdgcn_mfma_f32_16x16x32_bf16(
                        a, b, acc[f >> 1][f & 1], 0, 0, 0);
                }
            }
            #pragma unroll
            for (int kf = 2; kf < 6; ++kf) {
                bf16x8 a = *(const bf16x8*)&hAp[br * 16 + ml][kf * 32 + q * 8];
                #pragma unroll
                for (int f = 0; f < 8; ++f)
                    acc[f >> 1][f & 1] = __builtin_amdgcn_mfma_f32_16x16x32_bf16(
                        a, wreg[kf - 2][f], acc[f >> 1][f & 1], 0, 0, 0);
            }
            // kf6-7: wstr prefetched a full step ago
            #pragma unroll
            for (int kf = 6; kf < 8; ++kf) {
                bf16x8 a = *(const bf16x8*)&hAp[br * 16 + ml][kf * 32 + q * 8];
                #pragma unroll
                for (int f = 0; f < 8; ++f)
                    acc[f >> 1][f & 1] = __builtin_amdgcn_mfma_f32_16x16x32_bf16(
                        a, wstr[kf - 6][f], acc[f >> 1][f & 1], 0, 0, 0);
            }
            // reload wstr for t+1 (WAR orders issue here; drains under step)
            #pragma unroll
            for (int kf = 0; kf < 2; ++kf)
                #pragma unroll
                for (int f = 0; f < 8; ++f)
                    wstr[kf][f] = *(const bf16x8*)(wfb + ((6 + kf) * 8 + f) * 512);

            // activations + cell update (xv prefetched a full step ago)
            #pragma unroll
            for (int s = 0; s < 2; ++s) {
                const int j = ub + s * 16 + ml;
                float hv[4];
                #pragma unroll
                for (int r = 0; r < 4; ++r) {
                    float ig = sigm(acc[0][s][r] + bf2f((u16)xv[0][s * 4 + r]));
                    float fg = sigm(acc[1][s][r] + bf2f((u16)xv[1][s * 4 + r]));
                    float gg = tanh_f(acc[2][s][r] + bf2f((u16)xv[2][s * 4 + r]));
                    float og = sigm(acc[3][s][r] + bf2f((u16)xv[3][s * 4 + r]));
                    float cc = fg * c_[s * 4 + r] + ig * gg;
                    c_[s * 4 + r] = cc;
                    hv[r] = og * tanh_f(cc);
                }
                unsigned p01, p23;
                asm("v_cvt_pk_bf16_f32 %0, %1, %2" : "=v"(p01) : "v"(hv[0]), "v"(hv[1]));
                asm("v_cvt_pk_bf16_f32 %0, %1, %2" : "=v"(p23) : "v"(hv[2]), "v"(hv[3]));
                hAp[bw * 16 + q * 4 + 0][j] = (u16)p01;
                hAp[bw * 16 + q * 4 + 1][j] = (u16)(p01 >> 16);
                hAp[bw * 16 + q * 4 + 2][j] = (u16)p23;
                hAp[bw * 16 + q * 4 + 3][j] = (u16)(p23 >> 16);
                if (L == 1 && chunk == NCH - 1 && t == TCH - 1) {
                    #pragma unroll
                    for (int r = 0; r < 4; ++r)
                        hlast[(size_t)(bb0 + q * 4 + r) * 256 + j] = hv[r];
                }
            }
            // reload xv for t+1 (last step reads past chunk -- mapped, unused)
            xpt += XPSTEP;
            #pragma unroll
            for (int gi = 0; gi < 4; ++gi)
                xv[gi] = *(const bf16x8*)(xpt + gi * 4096);

            // publish h(t+1): only hA ds_writes gate the barrier
            asm volatile("s_waitcnt lgkmcnt(0)\n\ts_barrier" ::: "memory");

            if (L == 0)
                *(bf16x8*)&h0c[((size_t)t * 256 + bb0 + m_st) * 256 + j_st] =
                    *(const bf16x8*)&hAp[bw * 16 + m_st][j_st];
        }

        // persist state (TCH even -> final h is in buf 0)
        #pragma unroll
        for (int s = 0; s < 2; ++s)
            #pragma unroll
            for (int r = 0; r < 4; ++r)
                cs[(size_t)(bb0 + q * 4 + r) * 256 + ub + s * 16 + ml] = c_[s * 4 + r];
        {
            int m = tid >> 5, j0 = (tid & 31) * 8;
            *(bf16x8*)&hs[(size_t)(bb0 + m) * 256 + j0] = *(const bf16x8*)&hAp[m][j0];
        }
        return;
    }

    // =================== gemm (A: xp0 from x; B: xp1 from h0c) ===================
    const int role = (blockIdx.x < 288) ? 0 : 1;
    const int bid  = blockIdx.x - (role ? 288 : 32);
    const int chunk = role ? d - 2 : d;
    if (chunk < 0 || chunk >= NCH) return;

    const int K = role ? 256 : 64;
    const u16* Wp = role ? Wih1b : Wih0b;
    const float* bias = role ? bias1 : bias0;
    u16* out = (role ? xp1base : xp0base) + (size_t)(chunk & 1) * XPCH;
    const u16* A1 = h0cbase + (size_t)(chunk & 1) * H0CCH;   // role B source

    u16 (*As)[40] = (u16 (*)[40])SMEM;            // [128][40]
    u16 (*Bs)[40] = (u16 (*)[40])(SMEM + 5120);   // [256][40]

    const int mb = bid >> 2, nb = bid & 3;
    const int n0 = nb * 256;
    const int wave = tid >> 6, lane = tid & 63;
    const int wm = wave >> 2, wn = wave & 3;      // 2 x 4 wave grid -> 128x256 tile
    const int ml = lane & 15, q = lane >> 4;
    const int tloc = mb >> 1;
    const int bbas = (mb & 1) * 128;
    const int tt = role ? tloc : chunk * TCH + tloc;

    f32x4 acc[4][4];
    #pragma unroll
    for (int mi = 0; mi < 4; ++mi)
        #pragma unroll
        for (int ni = 0; ni < 4; ++ni)
            acc[mi][ni] = (f32x4)0.f;

    const int nk = K >> 5;
    for (int kt = 0; kt < nk; ++kt) {
        __syncthreads();
        {
            int row = tid >> 2, kb = tid & 3;
            if (role) {
                *(uint4*)&As[row][kb * 8] = *(const uint4*)(
                    A1 + (size_t)tt * 65536 + (size_t)(bbas + row) * 256 + kt * 32 + kb * 8);
            } else {
                const float* xs = x + (size_t)(bbas + row) * 32768 + (size_t)tt * 64
                                    + kt * 32 + kb * 8;
                float4 fa = *(const float4*)xs;
                float4 fb = *(const float4*)(xs + 4);
                uint4 v;
                v.x = f2bf(fa.x) | ((unsigned)f2bf(fa.y) << 16);
                v.y = f2bf(fa.z) | ((unsigned)f2bf(fa.w) << 16);
                v.z = f2bf(fb.x) | ((unsigned)f2bf(fb.y) << 16);
                v.w = f2bf(fb.z) | ((unsigned)f2bf(fb.w) << 16);
                *(uint4*)&As[row][kb * 8] = v;
            }
            #pragma unroll
            for (int i = 0; i < 2; ++i) {
                int c2 = tid + i * 512, r2 = c2 >> 2, k2 = c2 & 3;
                *(uint4*)&Bs[r2][k2 * 8] = *(const uint4*)(
                    Wp + (size_t)(n0 + r2) * K + kt * 32 + k2 * 8);
            }
        }
        __syncthreads();
        bf16x8 af[4], bfr[4];
        #pragma unroll
        for (int mi = 0; mi < 4; ++mi)
            af[mi] = *(const bf16x8*)&As[wm * 64 + mi * 16 + ml][q * 8];
        #pragma unroll
        for (int ni = 0; ni < 4; ++ni)
            bfr[ni] = *(const bf16x8*)&Bs[wn * 64 + ni * 16 + ml][q * 8];
        #pragma unroll
        for (int mi = 0; mi < 4; ++mi)
            #pragma unroll
            for (int ni = 0; ni < 4; ++ni)
                acc[mi][ni] = __builtin_amdgcn_mfma_f32_16x16x32_bf16(
                    af[mi], bfr[ni], acc[mi][ni], 0, 0, 0);
    }

    // epilogue: new xp index  el = (((tloc*16+blk2)*4+gi)*512 + tid_r)*8 + e
    #pragma unroll
    for (int ni = 0; ni < 4; ++ni) {
        int gc = n0 + wn * 64 + ni * 16 + ml;
        int gi = gc >> 8, u = gc & 255;
        int wv = u >> 5, s = (u >> 4) & 1, mlr = u & 15;
        float bv = bias[gc];
        #pragma unroll
        for (int mi = 0; mi < 4; ++mi) {
            int rowbase = bbas + wm * 64 + mi * 16;        // multiple of 16
            int blk2 = rowbase >> 4;
            size_t el0 = ((size_t)((tloc * 16 + blk2) * 4 + gi) * 512
                          + wv * 64 + q * 16 + mlr) * 8 + s * 4;
            #pragma unroll
            for (int rr = 0; rr < 4; ++rr)
                out[el0 + rr] = f2bf(acc[mi][ni][rr] + bv);
        }
    }
}

// ---------------- FC head ----------------
__global__ void fc_k(const float* __restrict__ h, const float* __restrict__ w,
                     const float* __restrict__ b, float* __restrict__ out)
{
    int bb = blockIdx.x, lane = threadIdx.x;
    float s = 0.f;
    for (int j = lane; j < 256; j += 64) s += h[bb * 256 + j] * w[j];
    #pragma unroll
    for (int off = 32; off > 0; off >>= 1) s += __shfl_down(s, off);
    if (lane == 0) out[bb] = s + b[0];
}

extern "C" void kernel_launch(void* const* d_in, const int* in_sizes, int n_in,
                              void* d_out, int out_size, void* d_ws, size_t ws_size,
                              hipStream_t stream)
{
    const float* x    = (const float*)d_in[0];
    const float* Wih0 = (const float*)d_in[1];
    const float* Whh0 = (const float*)d_in[2];
    const float* bih0 = (const float*)d_in[3];
    const float* bhh0 = (const float*)d_in[4];
    const float* Wih1 = (const float*)d_in[5];
    const float* Whh1 = (const float*)d_in[6];
    const float* bih1 = (const float*)d_in[7];
    const float* bhh1 = (const float*)d_in[8];
    const float* fcw  = (const float*)d_in[9];
    const float* fcb  = (const float*)d_in[10];
    float* out = (float*)d_out;

    // workspace layout, total ~75.6 MB
    char* ws = (char*)d_ws;
    u16*   xp0b  = (u16*)(ws);                  // 33554432  (2 chunks)
    u16*   xp1b  = (u16*)(ws + 33554432);       // 33554432  (2 chunks)
    u16*   h0cb  = (u16*)(ws + 67108864);       //  8388608  (2 chunks)
    u16*   Wih0b = (u16*)(ws + 75497472);       //   131072
    u16*   Whh0b = (u16*)(ws + 75628544);       //   524288
    u16*   Wih1b = (u16*)(ws + 76152832);       //   524288
    u16*   Whh1b = (u16*)(ws + 76677120);       //   524288
    float* bias0 = (float*)(ws + 77201408);     //     4096
    float* bias1 = (float*)(ws + 77205504);     //     4096
    u16*   hs0   = (u16*)(ws + 77209600);       //   131072
    float* cs0   = (float*)(ws + 77340672);     //   262144
    u16*   hs1   = (u16*)(ws + 77602816);       //   131072
    float* cs1   = (float*)(ws + 77733888);     //   262144
    float* h1l   = (float*)(ws + 77996032);     //   262144
    u16*   Whh0f = (u16*)(ws + 78258176);       //   524288  frag-order W
    u16*   Whh1f = (u16*)(ws + 78782464);       //   524288

    k_conv<<<256,  256, 0, stream>>>(Wih0, Wih0b, 65536);
    k_conv<<<1024, 256, 0, stream>>>(Whh0, Whh0b, 262144);
    k_conv<<<1024, 256, 0, stream>>>(Wih1, Wih1b, 262144);
    k_conv<<<1024, 256, 0, stream>>>(Whh1, Whh1b, 262144);
    k_bias<<<4, 256, 0, stream>>>(bih0, bhh0, bias0, 1024);
    k_bias<<<4, 256, 0, stream>>>(bih1, bhh1, bias1, 1024);
    k_wshuf<<<512, 64, 0, stream>>>(Whh0b, Whh0f);
    k_wshuf<<<512, 64, 0, stream>>>(Whh1b, Whh1f);

    for (int d = 0; d <= NCH + 2; ++d)   // d = 0..18
        mega<<<544, 512, 0, stream>>>(x, Wih0b, Whh0f, Wih1b, Whh1f,
                                      bias0, bias1, xp0b, xp1b, h0cb, h1l,
                                      hs0, cs0, hs1, cs1, d);
    fc_k<<<256, 64, 0, stream>>>(h1l, fcw, fcb, out);
}